// Round 3
// baseline (2209.848 us; speedup 1.0000x reference)
//
#include <hip/hip_runtime.h>
#include <math.h>

#define T_STEPS 512
#define BATCH   512

__device__ __forceinline__ float sigmoidf_(float x) {
    return 1.0f / (1.0f + __expf(-x));        // x<<0 -> 1/inf = 0, safe
}
__device__ __forceinline__ float tanhf_(float x) {
    float ax = fabsf(x);
    float e  = __expf(-2.0f * ax);            // in (0,1], never overflows
    float t  = (1.0f - e) / (1.0f + e);
    return copysignf(t, x);
}

// ---------------------------------------------------------------------------
// xg[r][j] = b_ih[j] + b_hh[j] + sum_k A[r][k] * W[j][k]
// Thread j owns W row j in registers (K <= 100 -> no spill). A staged in LDS,
// read as wave-uniform float4 broadcasts (conflict-free). 64 rows per block.
// ---------------------------------------------------------------------------
template<int K, int N, int NT>
__global__ __launch_bounds__(NT, 1) void xg_gemm_kernel(
    const float* __restrict__ A,    // [nrows, K]
    const float* __restrict__ W,    // [N, K]
    const float* __restrict__ bih, const float* __restrict__ bhh,
    float* __restrict__ xg)         // [nrows, N]
{
    __shared__ __align__(16) float As[64 * K];
    const int tid = threadIdx.x;

    float w[K];
    float bias = 0.0f;
    if (tid < N) {
        bias = bih[tid] + bhh[tid];
        #pragma unroll
        for (int k = 0; k < K; ++k) w[k] = W[tid * K + k];
    }

    const size_t r0 = (size_t)blockIdx.x * 64;
    const float4* Ag = (const float4*)(A + r0 * K);
    float4* As4 = (float4*)As;
    for (int i = tid; i < 64 * K / 4; i += NT) As4[i] = Ag[i];
    __syncthreads();

    if (tid < N) {
        for (int r = 0; r < 64; ++r) {
            const float4* a4 = (const float4*)(As + r * K);
            float acc0 = bias, acc1 = 0.0f;
            #pragma unroll
            for (int k4 = 0; k4 < K / 4; ++k4) {
                float4 v = a4[k4];
                acc0 = fmaf(v.x, w[4*k4+0], acc0);
                acc1 = fmaf(v.y, w[4*k4+1], acc1);
                acc0 = fmaf(v.z, w[4*k4+2], acc0);
                acc1 = fmaf(v.w, w[4*k4+3], acc1);
            }
            xg[(r0 + r) * N + tid] = acc0 + acc1;
        }
    }
}

// ---------------------------------------------------------------------------
// Layer-1 scan over one T-chunk. 512 blocks (1 batch row each, 2 blocks/CU).
// Gate thread j (<400): w_hh1 row (100 regs), xg read from global with
// 1-step register prefetch; h broadcast from LDS. Update threads (<100)
// keep c in registers. State (h via h1c last row, c via c1state) carries
// across chunk launches.
// ---------------------------------------------------------------------------
__global__ __launch_bounds__(448, 1) void scan1_kernel(
    const float* __restrict__ xg,     // [CH*B, 400] chunk-local
    const float* __restrict__ w_hh,   // [400, 100]
    float* __restrict__ h1c,          // [CH*B, 100] chunk-local
    float* __restrict__ c1state,      // [B, 100]
    int t0, int CH)
{
    __shared__ __align__(16) float h_s[100];
    __shared__ __align__(16) float g_s[400];

    const int tid  = threadIdx.x;
    const int brow = blockIdx.x;

    float w[100];
    if (tid < 400) {
        #pragma unroll
        for (int k = 0; k < 100; ++k) w[k] = w_hh[tid * 100 + k];
    }

    float c = 0.0f;
    if (tid < 100) {
        if (t0 == 0) {
            h_s[tid] = 0.0f;
        } else {
            h_s[tid] = h1c[((size_t)(CH - 1) * BATCH + brow) * 100 + tid];
            c        = c1state[(size_t)brow * 100 + tid];
        }
    }
    float xgv = (tid < 400) ? xg[(size_t)brow * 400 + tid] : 0.0f;
    __syncthreads();

    for (int tl = 0; tl < CH; ++tl) {
        float pre = (tid < 400 && tl + 1 < CH)
                  ? xg[((size_t)(tl + 1) * BATCH + brow) * 400 + tid] : 0.0f;
        if (tid < 400) {
            float a0 = xgv, a1 = 0.0f;
            const float4* hv = (const float4*)h_s;
            #pragma unroll
            for (int k4 = 0; k4 < 25; ++k4) {
                float4 v = hv[k4];
                a0 = fmaf(v.x, w[4*k4+0], a0);
                a1 = fmaf(v.y, w[4*k4+1], a1);
                a0 = fmaf(v.z, w[4*k4+2], a0);
                a1 = fmaf(v.w, w[4*k4+3], a1);
            }
            g_s[tid] = a0 + a1;
        }
        __syncthreads();
        xgv = pre;
        if (tid < 100) {
            float gi = g_s[tid],       gf = g_s[100 + tid];
            float gg = g_s[200 + tid], go = g_s[300 + tid];
            c = sigmoidf_(gf) * c + sigmoidf_(gi) * tanhf_(gg);
            float h = sigmoidf_(go) * tanhf_(c);
            h_s[tid] = h;
            h1c[((size_t)tl * BATCH + brow) * 100 + tid] = h;
        }
        __syncthreads();
    }
    if (tid < 100) c1state[(size_t)brow * 100 + tid] = c;
}

// ---------------------------------------------------------------------------
// Layers 2+3 + final linear, pipelined scan over one T-chunk.
//   iteration it: L2 step t0+it, L3 step t0+it-1, linear step t0+it-2.
// 512 blocks (1 batch row), 384 threads:
//   tid   0..199 : L2 gates (wa[0:50] = w_hh2 row; xg2 prefetched from global)
//   tid   0..49  : L2 update (c2)
//   tid 256..355 : L3 gates (wa[0:50] = w_ih3 row, wb[0:25] = w_hh3 row)
//   tid 256..280 : L3 update (c3)
//   tid 370      : final linear (wa[0:25] = w_lin)
// Register arrays manually unioned (wa[52], wb[28], zero-padded so float4
// dot-products over padded LDS are exact).
// ---------------------------------------------------------------------------
__global__ __launch_bounds__(384, 1) void scan23_kernel(
    const float* __restrict__ xg2,    // [CH*B, 200] chunk-local (biases folded)
    const float* __restrict__ w_hh2,  // [200, 50]
    const float* __restrict__ w_ih3,  // [100, 50]
    const float* __restrict__ w_hh3,  // [100, 25]
    const float* __restrict__ b_ih3, const float* __restrict__ b_hh3,
    const float* __restrict__ w_lin, const float* __restrict__ b_lin,
    float* __restrict__ out,          // [T*B]
    float* __restrict__ h2state, float* __restrict__ c2state,  // [B,50]
    float* __restrict__ h3state, float* __restrict__ c3state,  // [B,25]
    int t0, int CH)
{
    __shared__ __align__(16) float h2_s[52];
    __shared__ __align__(16) float x3_s[2][52];
    __shared__ __align__(16) float h3_s[28];
    __shared__ __align__(16) float h3o_s[2][28];
    __shared__ __align__(16) float g2_s[200];
    __shared__ __align__(16) float g3_s[100];

    const int tid  = threadIdx.x;
    const int brow = blockIdx.x;

    float wa[52], wb[28], bias = 0.0f;
    #pragma unroll
    for (int k = 0; k < 52; ++k) wa[k] = 0.0f;
    #pragma unroll
    for (int k = 0; k < 28; ++k) wb[k] = 0.0f;

    if (tid < 200) {
        #pragma unroll
        for (int k = 0; k < 50; ++k) wa[k] = w_hh2[tid * 50 + k];
    } else if (tid >= 256 && tid < 356) {
        int j = tid - 256;
        bias = b_ih3[j] + b_hh3[j];
        #pragma unroll
        for (int k = 0; k < 50; ++k) wa[k] = w_ih3[j * 50 + k];
        #pragma unroll
        for (int k = 0; k < 25; ++k) wb[k] = w_hh3[j * 25 + k];
    } else if (tid == 370) {
        bias = b_lin[0];
        #pragma unroll
        for (int k = 0; k < 25; ++k) wa[k] = w_lin[k];
    }

    float c2 = 0.0f, c3 = 0.0f;
    // zero pads (and poison-proof every float4-read slot)
    if (tid < 52)  { h2_s[tid] = 0.0f; x3_s[0][tid] = 0.0f; x3_s[1][tid] = 0.0f; }
    if (tid >= 52 && tid < 80)  h3_s[tid - 52] = 0.0f;
    if (tid >= 80 && tid < 108) h3o_s[0][tid - 80] = 0.0f;
    if (tid >= 108 && tid < 136) h3o_s[1][tid - 108] = 0.0f;
    __syncthreads();
    if (t0 > 0) {
        if (tid < 50) {
            h2_s[tid] = h2state[(size_t)brow * 50 + tid];
            c2        = c2state[(size_t)brow * 50 + tid];
        }
        if (tid >= 256 && tid < 281) {
            int u = tid - 256;
            h3_s[u] = h3state[(size_t)brow * 25 + u];
            c3      = c3state[(size_t)brow * 25 + u];
        }
    }
    float xgv = (tid < 200) ? xg2[(size_t)brow * 200 + tid] : 0.0f;
    __syncthreads();

    for (int it = 0; it < CH + 2; ++it) {
        // ---------------- phase A ----------------
        float pre = (tid < 200 && it + 1 < CH)
                  ? xg2[((size_t)(it + 1) * BATCH + brow) * 200 + tid] : 0.0f;

        if (tid < 200 && it < CH) {                 // L2 gates, step t0+it
            float a0 = xgv, a1 = 0.0f;
            const float4* hv = (const float4*)h2_s;
            #pragma unroll
            for (int k4 = 0; k4 < 13; ++k4) {
                float4 v = hv[k4];
                a0 = fmaf(v.x, wa[4*k4+0], a0);
                a1 = fmaf(v.y, wa[4*k4+1], a1);
                a0 = fmaf(v.z, wa[4*k4+2], a0);
                a1 = fmaf(v.w, wa[4*k4+3], a1);
            }
            g2_s[tid] = a0 + a1;
        }

        if (tid >= 256 && tid < 356 && it >= 1 && it <= CH) {  // L3 gates, step t0+it-1
            float a0 = bias, a1 = 0.0f;
            const float4* xv = (const float4*)x3_s[(it - 1) & 1];
            #pragma unroll
            for (int k4 = 0; k4 < 13; ++k4) {
                float4 v = xv[k4];
                a0 = fmaf(v.x, wa[4*k4+0], a0);
                a1 = fmaf(v.y, wa[4*k4+1], a1);
                a0 = fmaf(v.z, wa[4*k4+2], a0);
                a1 = fmaf(v.w, wa[4*k4+3], a1);
            }
            const float4* hv = (const float4*)h3_s;
            #pragma unroll
            for (int k4 = 0; k4 < 7; ++k4) {
                float4 v = hv[k4];
                a0 = fmaf(v.x, wb[4*k4+0], a0);
                a1 = fmaf(v.y, wb[4*k4+1], a1);
                a0 = fmaf(v.z, wb[4*k4+2], a0);
                a1 = fmaf(v.w, wb[4*k4+3], a1);
            }
            g3_s[tid - 256] = a0 + a1;
        }

        if (tid == 370 && it >= 2) {               // linear, step t0+it-2
            float o = bias;
            const float4* hv = (const float4*)h3o_s[(it - 2) & 1];
            #pragma unroll
            for (int k4 = 0; k4 < 7; ++k4) {
                float4 v = hv[k4];
                o = fmaf(v.x, wa[4*k4+0], o);
                o = fmaf(v.y, wa[4*k4+1], o);
                o = fmaf(v.z, wa[4*k4+2], o);
                o = fmaf(v.w, wa[4*k4+3], o);
            }
            out[(size_t)(t0 + it - 2) * BATCH + brow] = o;
        }
        __syncthreads();

        // ---------------- phase B ----------------
        if (tid < 200) xgv = pre;

        if (tid < 50 && it < CH) {                  // L2 update
            float gi = g2_s[tid],       gf = g2_s[50 + tid];
            float gg = g2_s[100 + tid], go = g2_s[150 + tid];
            c2 = sigmoidf_(gf) * c2 + sigmoidf_(gi) * tanhf_(gg);
            float h = sigmoidf_(go) * tanhf_(c2);
            h2_s[tid] = h;
            x3_s[it & 1][tid] = h;
        }

        if (tid >= 256 && tid < 281 && it >= 1 && it <= CH) {  // L3 update
            int u = tid - 256;
            float gi = g3_s[u],      gf = g3_s[25 + u];
            float gg = g3_s[50 + u], go = g3_s[75 + u];
            c3 = sigmoidf_(gf) * c3 + sigmoidf_(gi) * tanhf_(gg);
            float h = sigmoidf_(go) * tanhf_(c3);
            h3_s[u] = h;
            h3o_s[(it - 1) & 1][u] = h;
        }
        __syncthreads();
    }

    if (tid < 50) {
        h2state[(size_t)brow * 50 + tid] = h2_s[tid];
        c2state[(size_t)brow * 50 + tid] = c2;
    }
    if (tid >= 256 && tid < 281) {
        int u = tid - 256;
        h3state[(size_t)brow * 25 + u] = h3_s[u];
        c3state[(size_t)brow * 25 + u] = c3;
    }
}

extern "C" void kernel_launch(void* const* d_in, const int* in_sizes, int n_in,
                              void* d_out, int out_size, void* d_ws, size_t ws_size,
                              hipStream_t stream)
{
    const float* x     = (const float*)d_in[0];
    const float* w_ih1 = (const float*)d_in[1];
    const float* w_hh1 = (const float*)d_in[2];
    const float* b_ih1 = (const float*)d_in[3];
    const float* b_hh1 = (const float*)d_in[4];
    const float* w_ih2 = (const float*)d_in[5];
    const float* w_hh2 = (const float*)d_in[6];
    const float* b_ih2 = (const float*)d_in[7];
    const float* b_hh2 = (const float*)d_in[8];
    const float* w_ih3 = (const float*)d_in[9];
    const float* w_hh3 = (const float*)d_in[10];
    const float* b_ih3 = (const float*)d_in[11];
    const float* b_hh3 = (const float*)d_in[12];
    const float* w_lin = (const float*)d_in[13];
    const float* b_lin = (const float*)d_in[14];
    float* out = (float*)d_out;

    // Chunked workspace: pick largest CH whose buffers fit ws_size.
    // bytes(CH) = CH*B*4*(400 + 100 + 200) + state arrays
    const size_t state_bytes = (size_t)BATCH * (100 + 50 + 50 + 25 + 25) * sizeof(float);
    int CH = 0;
    for (int c = 128; c >= 8; c >>= 1) {
        size_t need = (size_t)c * BATCH * 700 * sizeof(float) + state_bytes;
        if (need <= ws_size) { CH = c; break; }
    }
    if (CH == 0) return;  // soft-fail: workspace too small

    char* ws = (char*)d_ws;
    float* xg1c    = (float*)ws;                                   // CH*B*400
    float* h1c     = xg1c + (size_t)CH * BATCH * 400;              // CH*B*100
    float* xg2c    = h1c  + (size_t)CH * BATCH * 100;              // CH*B*200
    float* c1state = xg2c + (size_t)CH * BATCH * 200;              // B*100
    float* h2state = c1state + (size_t)BATCH * 100;                // B*50
    float* c2state = h2state + (size_t)BATCH * 50;                 // B*50
    float* h3state = c2state + (size_t)BATCH * 50;                 // B*25
    float* c3state = h3state + (size_t)BATCH * 25;                 // B*25

    const int rowtiles = CH * BATCH / 64;

    for (int t0 = 0; t0 < T_STEPS; t0 += CH) {
        xg_gemm_kernel<64, 400, 448><<<rowtiles, 448, 0, stream>>>(
            x + (size_t)t0 * BATCH * 64, w_ih1, b_ih1, b_hh1, xg1c);
        scan1_kernel<<<BATCH, 448, 0, stream>>>(xg1c, w_hh1, h1c, c1state, t0, CH);
        xg_gemm_kernel<100, 200, 256><<<rowtiles, 256, 0, stream>>>(
            h1c, w_ih2, b_ih2, b_hh2, xg2c);
        scan23_kernel<<<BATCH, 384, 0, stream>>>(
            xg2c, w_hh2, w_ih3, w_hh3, b_ih3, b_hh3, w_lin, b_lin, out,
            h2state, c2state, h3state, c3state, t0, CH);
    }
}

// Round 4
// 1898.586 us; speedup vs baseline: 1.1639x; 1.1639x over previous
//
#include <hip/hip_runtime.h>
#include <math.h>

#define T_STEPS 512
#define BATCH   512

__device__ __forceinline__ float sigmoidf_(float x) {
    return 1.0f / (1.0f + __expf(-x));        // x<<0 -> 1/inf = 0, safe
}
__device__ __forceinline__ float tanhf_(float x) {
    float ax = fabsf(x);
    float e  = __expf(-2.0f * ax);            // in (0,1], never overflows
    float t  = (1.0f - e) / (1.0f + e);
    return copysignf(t, x);
}

// ---------------------------------------------------------------------------
// gemm1: xg[r][j] = b_ih[j]+b_hh[j] + sum_k A[r][k]*W[j][k], K=64, N=400.
// Thread j owns W row (64 regs — empirically non-spilling). 64 rows/block.
// ---------------------------------------------------------------------------
template<int K, int N, int NT>
__global__ __launch_bounds__(NT) void xg_gemm_kernel(
    const float* __restrict__ A, const float* __restrict__ W,
    const float* __restrict__ bih, const float* __restrict__ bhh,
    float* __restrict__ xg)
{
    __shared__ __align__(16) float As[64 * K];
    const int tid = threadIdx.x;

    float w[K];
    float bias = 0.0f;
    if (tid < N) {
        bias = bih[tid] + bhh[tid];
        #pragma unroll
        for (int k = 0; k < K; ++k) w[k] = W[tid * K + k];
    }

    const size_t r0 = (size_t)blockIdx.x * 64;
    const float4* Ag = (const float4*)(A + r0 * K);
    float4* As4 = (float4*)As;
    for (int i = tid; i < 64 * K / 4; i += NT) As4[i] = Ag[i];
    __syncthreads();

    if (tid < N) {
        for (int r = 0; r < 64; ++r) {
            const float4* a4 = (const float4*)(As + r * K);
            float acc0 = bias, acc1 = 0.0f;
            #pragma unroll
            for (int k4 = 0; k4 < K / 4; ++k4) {
                float4 v = a4[k4];
                acc0 = fmaf(v.x, w[4*k4+0], acc0);
                acc1 = fmaf(v.y, w[4*k4+1], acc1);
                acc0 = fmaf(v.z, w[4*k4+2], acc0);
                acc1 = fmaf(v.w, w[4*k4+3], acc1);
            }
            xg[(r0 + r) * N + tid] = acc0 + acc1;
        }
    }
}

// ---------------------------------------------------------------------------
// gemm2: K=100, N=200, split-K slots (no thread holds >52 weights).
// 448 threads: tid<400 -> slot (j = tid%200, q = tid/200) holds
// w_ih2[j][52q : 52q+52] (zero-padded past 100). 64 rows/block in LDS
// (rows padded to 104 floats, pad = 0). 8-row groups: slot computes 8
// partial dots (broadcast float4 reads), partials combined via LDS ps.
// ---------------------------------------------------------------------------
__global__ __launch_bounds__(448) void gemm2_kernel(
    const float* __restrict__ A,      // [rows,100] = h1 chunk
    const float* __restrict__ W,      // [200,100]  = w_ih2
    const float* __restrict__ bih, const float* __restrict__ bhh,
    float* __restrict__ xg)           // [rows,200]
{
    __shared__ __align__(16) float As[64 * 104];
    __shared__ __align__(16) float ps[8][400];

    const int tid = threadIdx.x;
    const int q   = (tid < 400) ? tid / 200 : 0;
    const int j   = (tid < 400) ? tid % 200 : 0;
    const bool slot = (tid < 400);

    float w[52];
    float bias = 0.0f;
    if (slot) {
        if (q == 0) bias = bih[j] + bhh[j];
        #pragma unroll
        for (int i = 0; i < 52; ++i) {
            int k = 52 * q + i;
            w[i] = (k < 100) ? W[j * 100 + k] : 0.0f;
        }
    }

    const size_t r0 = (size_t)blockIdx.x * 64;
    const float2* A2 = (const float2*)(A + r0 * 100);
    float2* As2 = (float2*)As;
    for (int i = tid; i < 64 * 50; i += 448) {
        int r = i / 50, k2 = i % 50;
        As2[r * 52 + k2] = A2[i];
    }
    if (tid < 64) *(float4*)&As[tid * 104 + 100] = float4{0.f, 0.f, 0.f, 0.f};
    __syncthreads();

    const float4* As4 = (const float4*)As;
    for (int g = 0; g < 8; ++g) {
        float acc[8];
        if (slot) {
            #pragma unroll
            for (int rr = 0; rr < 8; ++rr) acc[rr] = bias;
            #pragma unroll
            for (int k4 = 0; k4 < 13; ++k4) {
                #pragma unroll
                for (int rr = 0; rr < 8; ++rr) {
                    float4 v = As4[(g * 8 + rr) * 26 + q * 13 + k4];
                    acc[rr] = fmaf(v.x, w[4*k4+0], acc[rr]);
                    acc[rr] = fmaf(v.y, w[4*k4+1], acc[rr]);
                    acc[rr] = fmaf(v.z, w[4*k4+2], acc[rr]);
                    acc[rr] = fmaf(v.w, w[4*k4+3], acc[rr]);
                }
            }
            #pragma unroll
            for (int rr = 0; rr < 8; ++rr) ps[rr][j * 2 + q] = acc[rr];
        }
        __syncthreads();
        if (tid < 200) {
            #pragma unroll
            for (int rr = 0; rr < 8; ++rr) {
                float2 p = *(const float2*)&ps[rr][tid * 2];
                xg[(r0 + g * 8 + rr) * 200 + tid] = p.x + p.y;
            }
        }
        __syncthreads();
    }
}

// ---------------------------------------------------------------------------
// scan1: layer-1 recurrence, split-K slots. 256 blocks (2 batch rows,
// 1 block/CU at 13 waves), 832 threads:
//   tid 0..399   : slot (j=tid,     q=0) — w_hh1[j][0:52],  xg feed + prefetch
//   tid 416..815 : slot (j=tid-416, q=1) — w_hh1[j][52:104] (zero-padded)
//   tid 0..199   : update threads (bn=tid/100, u=tid%100), c in register
// h in LDS h_s[2][104] (pad=0), partials in ps[2][400][2].
// ---------------------------------------------------------------------------
__global__ __launch_bounds__(832) void scan1_kernel(
    const float* __restrict__ xg,     // [CH*B, 400] chunk-local
    const float* __restrict__ w_hh,   // [400, 100]
    float* __restrict__ h1c,          // [CH*B, 100] chunk-local
    float* __restrict__ c1state,      // [B, 100]
    int t0, int CH)
{
    __shared__ __align__(16) float h_s[2][104];
    __shared__ __align__(16) float ps[2][400][2];

    const int tid   = threadIdx.x;
    const int q     = (tid >= 416) ? 1 : 0;
    const int j     = tid - 416 * q;
    const bool slot = (j < 400);
    const int brow0 = blockIdx.x * 2;

    float w[52];
    if (slot) {
        #pragma unroll
        for (int i = 0; i < 52; ++i) {
            int k = 52 * q + i;
            w[i] = (k < 100) ? w_hh[j * 100 + k] : 0.0f;
        }
    }

    float c = 0.0f;
    if (tid < 200) {
        int bn = tid / 100, u = tid % 100;
        if (t0 == 0) {
            h_s[bn][u] = 0.0f;
        } else {
            h_s[bn][u] = h1c[((size_t)(CH - 1) * BATCH + brow0 + bn) * 100 + u];
            c          = c1state[(size_t)(brow0 + bn) * 100 + u];
        }
    }
    if (tid >= 200 && tid < 208) {          // zero the float4 pad
        int i = tid - 200;
        h_s[i / 4][100 + (i & 3)] = 0.0f;
    }

    float xgv0 = 0.0f, xgv1 = 0.0f;
    if (slot && q == 0) {
        xgv0 = xg[(size_t)brow0 * 400 + j];
        xgv1 = xg[(size_t)(brow0 + 1) * 400 + j];
    }
    __syncthreads();

    for (int tl = 0; tl < CH; ++tl) {
        float pre0 = 0.0f, pre1 = 0.0f;
        if (slot && q == 0 && tl + 1 < CH) {
            pre0 = xg[((size_t)(tl + 1) * BATCH + brow0) * 400 + j];
            pre1 = xg[((size_t)(tl + 1) * BATCH + brow0 + 1) * 400 + j];
        }
        if (slot) {
            float a00 = xgv0, a01 = 0.0f, a10 = xgv1, a11 = 0.0f;
            const float4* h0 = (const float4*)h_s[0] + q * 13;
            const float4* h1 = (const float4*)h_s[1] + q * 13;
            #pragma unroll
            for (int k4 = 0; k4 < 13; ++k4) {
                float4 v0 = h0[k4], v1 = h1[k4];
                a00 = fmaf(v0.x, w[4*k4+0], a00); a10 = fmaf(v1.x, w[4*k4+0], a10);
                a01 = fmaf(v0.y, w[4*k4+1], a01); a11 = fmaf(v1.y, w[4*k4+1], a11);
                a00 = fmaf(v0.z, w[4*k4+2], a00); a10 = fmaf(v1.z, w[4*k4+2], a10);
                a01 = fmaf(v0.w, w[4*k4+3], a01); a11 = fmaf(v1.w, w[4*k4+3], a11);
            }
            ps[0][j][q] = a00 + a01;
            ps[1][j][q] = a10 + a11;
        }
        __syncthreads();
        xgv0 = pre0; xgv1 = pre1;
        if (tid < 200) {
            int bn = tid / 100, u = tid % 100;
            float2 pi = *(const float2*)&ps[bn][u][0];
            float2 pf = *(const float2*)&ps[bn][100 + u][0];
            float2 pg = *(const float2*)&ps[bn][200 + u][0];
            float2 po = *(const float2*)&ps[bn][300 + u][0];
            float gi = pi.x + pi.y, gf = pf.x + pf.y;
            float gg = pg.x + pg.y, go = po.x + po.y;
            c = sigmoidf_(gf) * c + sigmoidf_(gi) * tanhf_(gg);
            float h = sigmoidf_(go) * tanhf_(c);
            h_s[bn][u] = h;
            h1c[((size_t)tl * BATCH + brow0 + bn) * 100 + u] = h;
        }
        __syncthreads();
    }
    if (tid < 200) {
        int bn = tid / 100, u = tid % 100;
        c1state[(size_t)(brow0 + bn) * 100 + u] = c;
    }
}

// ---------------------------------------------------------------------------
// scan23: layers 2+3 + linear, pipelined (unchanged from round 3 — measured
// within budget; max per-thread weight array 52+28=80 floats, non-spilling).
// ---------------------------------------------------------------------------
__global__ __launch_bounds__(384) void scan23_kernel(
    const float* __restrict__ xg2,    // [CH*B, 200] chunk-local (biases folded)
    const float* __restrict__ w_hh2,  // [200, 50]
    const float* __restrict__ w_ih3,  // [100, 50]
    const float* __restrict__ w_hh3,  // [100, 25]
    const float* __restrict__ b_ih3, const float* __restrict__ b_hh3,
    const float* __restrict__ w_lin, const float* __restrict__ b_lin,
    float* __restrict__ out,          // [T*B]
    float* __restrict__ h2state, float* __restrict__ c2state,  // [B,50]
    float* __restrict__ h3state, float* __restrict__ c3state,  // [B,25]
    int t0, int CH)
{
    __shared__ __align__(16) float h2_s[52];
    __shared__ __align__(16) float x3_s[2][52];
    __shared__ __align__(16) float h3_s[28];
    __shared__ __align__(16) float h3o_s[2][28];
    __shared__ __align__(16) float g2_s[200];
    __shared__ __align__(16) float g3_s[100];

    const int tid  = threadIdx.x;
    const int brow = blockIdx.x;

    float wa[52], wb[28], bias = 0.0f;
    #pragma unroll
    for (int k = 0; k < 52; ++k) wa[k] = 0.0f;
    #pragma unroll
    for (int k = 0; k < 28; ++k) wb[k] = 0.0f;

    if (tid < 200) {
        #pragma unroll
        for (int k = 0; k < 50; ++k) wa[k] = w_hh2[tid * 50 + k];
    } else if (tid >= 256 && tid < 356) {
        int jj = tid - 256;
        bias = b_ih3[jj] + b_hh3[jj];
        #pragma unroll
        for (int k = 0; k < 50; ++k) wa[k] = w_ih3[jj * 50 + k];
        #pragma unroll
        for (int k = 0; k < 25; ++k) wb[k] = w_hh3[jj * 25 + k];
    } else if (tid == 370) {
        bias = b_lin[0];
        #pragma unroll
        for (int k = 0; k < 25; ++k) wa[k] = w_lin[k];
    }

    float c2 = 0.0f, c3 = 0.0f;
    if (tid < 52)  { h2_s[tid] = 0.0f; x3_s[0][tid] = 0.0f; x3_s[1][tid] = 0.0f; }
    if (tid >= 52 && tid < 80)  h3_s[tid - 52] = 0.0f;
    if (tid >= 80 && tid < 108) h3o_s[0][tid - 80] = 0.0f;
    if (tid >= 108 && tid < 136) h3o_s[1][tid - 108] = 0.0f;
    __syncthreads();
    if (t0 > 0) {
        if (tid < 50) {
            h2_s[tid] = h2state[(size_t)brow * 50 + tid];
            c2        = c2state[(size_t)brow * 50 + tid];
        }
        if (tid >= 256 && tid < 281) {
            int u = tid - 256;
            h3_s[u] = h3state[(size_t)brow * 25 + u];
            c3      = c3state[(size_t)brow * 25 + u];
        }
    }
    float xgv = (tid < 200) ? xg2[(size_t)brow * 200 + tid] : 0.0f;
    __syncthreads();

    for (int it = 0; it < CH + 2; ++it) {
        float pre = (tid < 200 && it + 1 < CH)
                  ? xg2[((size_t)(it + 1) * BATCH + brow) * 200 + tid] : 0.0f;

        if (tid < 200 && it < CH) {                 // L2 gates, step t0+it
            float a0 = xgv, a1 = 0.0f;
            const float4* hv = (const float4*)h2_s;
            #pragma unroll
            for (int k4 = 0; k4 < 13; ++k4) {
                float4 v = hv[k4];
                a0 = fmaf(v.x, wa[4*k4+0], a0);
                a1 = fmaf(v.y, wa[4*k4+1], a1);
                a0 = fmaf(v.z, wa[4*k4+2], a0);
                a1 = fmaf(v.w, wa[4*k4+3], a1);
            }
            g2_s[tid] = a0 + a1;
        }

        if (tid >= 256 && tid < 356 && it >= 1 && it <= CH) {  // L3 gates
            float a0 = bias, a1 = 0.0f;
            const float4* xv = (const float4*)x3_s[(it - 1) & 1];
            #pragma unroll
            for (int k4 = 0; k4 < 13; ++k4) {
                float4 v = xv[k4];
                a0 = fmaf(v.x, wa[4*k4+0], a0);
                a1 = fmaf(v.y, wa[4*k4+1], a1);
                a0 = fmaf(v.z, wa[4*k4+2], a0);
                a1 = fmaf(v.w, wa[4*k4+3], a1);
            }
            const float4* hv = (const float4*)h3_s;
            #pragma unroll
            for (int k4 = 0; k4 < 7; ++k4) {
                float4 v = hv[k4];
                a0 = fmaf(v.x, wb[4*k4+0], a0);
                a1 = fmaf(v.y, wb[4*k4+1], a1);
                a0 = fmaf(v.z, wb[4*k4+2], a0);
                a1 = fmaf(v.w, wb[4*k4+3], a1);
            }
            g3_s[tid - 256] = a0 + a1;
        }

        if (tid == 370 && it >= 2) {               // linear
            float o = bias;
            const float4* hv = (const float4*)h3o_s[(it - 2) & 1];
            #pragma unroll
            for (int k4 = 0; k4 < 7; ++k4) {
                float4 v = hv[k4];
                o = fmaf(v.x, wa[4*k4+0], o);
                o = fmaf(v.y, wa[4*k4+1], o);
                o = fmaf(v.z, wa[4*k4+2], o);
                o = fmaf(v.w, wa[4*k4+3], o);
            }
            out[(size_t)(t0 + it - 2) * BATCH + brow] = o;
        }
        __syncthreads();

        if (tid < 200) xgv = pre;

        if (tid < 50 && it < CH) {                  // L2 update
            float gi = g2_s[tid],       gf = g2_s[50 + tid];
            float gg = g2_s[100 + tid], go = g2_s[150 + tid];
            c2 = sigmoidf_(gf) * c2 + sigmoidf_(gi) * tanhf_(gg);
            float h = sigmoidf_(go) * tanhf_(c2);
            h2_s[tid] = h;
            x3_s[it & 1][tid] = h;
        }

        if (tid >= 256 && tid < 281 && it >= 1 && it <= CH) {  // L3 update
            int u = tid - 256;
            float gi = g3_s[u],      gf = g3_s[25 + u];
            float gg = g3_s[50 + u], go = g3_s[75 + u];
            c3 = sigmoidf_(gf) * c3 + sigmoidf_(gi) * tanhf_(gg);
            float h = sigmoidf_(go) * tanhf_(c3);
            h3_s[u] = h;
            h3o_s[(it - 1) & 1][u] = h;
        }
        __syncthreads();
    }

    if (tid < 50) {
        h2state[(size_t)brow * 50 + tid] = h2_s[tid];
        c2state[(size_t)brow * 50 + tid] = c2;
    }
    if (tid >= 256 && tid < 281) {
        int u = tid - 256;
        h3state[(size_t)brow * 25 + u] = h3_s[u];
        c3state[(size_t)brow * 25 + u] = c3;
    }
}

extern "C" void kernel_launch(void* const* d_in, const int* in_sizes, int n_in,
                              void* d_out, int out_size, void* d_ws, size_t ws_size,
                              hipStream_t stream)
{
    const float* x     = (const float*)d_in[0];
    const float* w_ih1 = (const float*)d_in[1];
    const float* w_hh1 = (const float*)d_in[2];
    const float* b_ih1 = (const float*)d_in[3];
    const float* b_hh1 = (const float*)d_in[4];
    const float* w_ih2 = (const float*)d_in[5];
    const float* w_hh2 = (const float*)d_in[6];
    const float* b_ih2 = (const float*)d_in[7];
    const float* b_hh2 = (const float*)d_in[8];
    const float* w_ih3 = (const float*)d_in[9];
    const float* w_hh3 = (const float*)d_in[10];
    const float* b_ih3 = (const float*)d_in[11];
    const float* b_hh3 = (const float*)d_in[12];
    const float* w_lin = (const float*)d_in[13];
    const float* b_lin = (const float*)d_in[14];
    float* out = (float*)d_out;

    const size_t state_bytes = (size_t)BATCH * (100 + 50 + 50 + 25 + 25) * sizeof(float);
    int CH = 0;
    for (int c = 128; c >= 8; c >>= 1) {
        size_t need = (size_t)c * BATCH * 700 * sizeof(float) + state_bytes;
        if (need <= ws_size) { CH = c; break; }
    }
    if (CH == 0) return;  // soft-fail: workspace too small

    char* ws = (char*)d_ws;
    float* xg1c    = (float*)ws;                                   // CH*B*400
    float* h1c     = xg1c + (size_t)CH * BATCH * 400;              // CH*B*100
    float* xg2c    = h1c  + (size_t)CH * BATCH * 100;              // CH*B*200
    float* c1state = xg2c + (size_t)CH * BATCH * 200;              // B*100
    float* h2state = c1state + (size_t)BATCH * 100;                // B*50
    float* c2state = h2state + (size_t)BATCH * 50;                 // B*50
    float* h3state = c2state + (size_t)BATCH * 50;                 // B*25
    float* c3state = h3state + (size_t)BATCH * 25;                 // B*25

    const int rowtiles = CH * BATCH / 64;

    for (int t0 = 0; t0 < T_STEPS; t0 += CH) {
        xg_gemm_kernel<64, 400, 448><<<rowtiles, 448, 0, stream>>>(
            x + (size_t)t0 * BATCH * 64, w_ih1, b_ih1, b_hh1, xg1c);
        scan1_kernel<<<BATCH / 2, 832, 0, stream>>>(xg1c, w_hh1, h1c, c1state, t0, CH);
        gemm2_kernel<<<rowtiles, 448, 0, stream>>>(h1c, w_ih2, b_ih2, b_hh2, xg2c);
        scan23_kernel<<<BATCH, 384, 0, stream>>>(
            xg2c, w_hh2, w_ih3, w_hh3, b_ih3, b_hh3, w_lin, b_lin, out,
            h2state, c2state, h3state, c3state, t0, CH);
    }
}